// Round 3
// baseline (1265.135 us; speedup 1.0000x reference)
//
#include <hip/hip_runtime.h>

#define NB 16384
#define ND 768
#define NF 8192
#define MAXC 1024

typedef __attribute__((ext_vector_type(8))) short bf16x8;
typedef __attribute__((ext_vector_type(4))) float f32x4;

__device__ inline unsigned short f2bf(float f) {
  unsigned u = __float_as_uint(f);
  unsigned r = (u + 0x7FFFu + ((u >> 16) & 1u)) >> 16;
  return (unsigned short)r;
}

// ---------------------------------------------------------------------------
__global__ __launch_bounds__(256) void cvt_bf16_k(const float* __restrict__ in,
                                                  unsigned short* __restrict__ out) {
  size_t t = (size_t)blockIdx.x * 256 + threadIdx.x;
  const float4* i4 = (const float4*)in;
  float4 a = i4[t * 2], b = i4[t * 2 + 1];
  ushort4 lo = make_ushort4(f2bf(a.x), f2bf(a.y), f2bf(a.z), f2bf(a.w));
  ushort4 hi = make_ushort4(f2bf(b.x), f2bf(b.y), f2bf(b.z), f2bf(b.w));
  ((ushort4*)out)[t * 2] = lo;
  ((ushort4*)out)[t * 2 + 1] = hi;
}

// ---------------------------------------------------------------------------
__global__ __launch_bounds__(256) void beta_k(const float* __restrict__ W_enc,
                                              const float* __restrict__ b_enc,
                                              const float* __restrict__ dec_bias,
                                              float* __restrict__ beta) {
  int f = blockIdx.x * 4 + (threadIdx.x >> 6);
  int lane = threadIdx.x & 63;
  const float* wr = W_enc + (size_t)f * ND;
  float s = 0.f;
  for (int d = lane; d < ND; d += 64) s += dec_bias[d] * wr[d];
  for (int off = 32; off; off >>= 1) s += __shfl_down(s, off);
  if (lane == 0) beta[f] = b_enc[f] - s;
}

// ---------------------------------------------------------------------------
__global__ __launch_bounds__(256) void transpose_k(const float* __restrict__ in,
                                                   float* __restrict__ out,
                                                   int R, int C) {
  __shared__ float tile[32][33];
  int lx = threadIdx.x & 31;
  int ty = threadIdx.x >> 5;
  int x = blockIdx.x * 32 + lx;
  for (int j = ty; j < 32; j += 8) {
    int y = blockIdx.y * 32 + j;
    tile[j][lx] = in[(size_t)y * C + x];
  }
  __syncthreads();
  int xo = blockIdx.y * 32 + lx;
  for (int j = ty; j < 32; j += 8) {
    int yo = blockIdx.x * 32 + j;
    out[(size_t)yo * R + xo] = tile[lx][j];
  }
}

// ---------------------------------------------------------------------------
// bf16 MFMA GEMM (m97 structure) + XCD-aware bijective swizzle (nwg%8==0).
__global__ __launch_bounds__(256) void enc_gemm_bf16(
    const unsigned short* __restrict__ Xb, const unsigned short* __restrict__ Wb,
    const float* __restrict__ beta, unsigned short* __restrict__ acts) {
  __shared__ __align__(1024) unsigned short As[128 * 64];
  __shared__ __align__(1024) unsigned short Bs[128 * 64];
  const int tid = threadIdx.x;
  const int wave = tid >> 6, lane = tid & 63;
  const int wm = wave >> 1, wn = wave & 1;

  const int nwg = gridDim.x * gridDim.y;
  const int orig = blockIdx.y * gridDim.x + blockIdx.x;
  const int tileid = (orig & 7) * (nwg >> 3) + (orig >> 3);
  const int brow = (tileid / gridDim.x) << 7;
  const int bcol = (tileid % gridDim.x) << 7;

  f32x4 acc[4][4] = {};

  const int srow = tid >> 3;
  const int scol = (tid & 7) << 3;
  const unsigned short* gA = Xb + (size_t)(brow + srow) * ND + scol;
  const unsigned short* gB = Wb + (size_t)(bcol + srow) * ND + scol;

  for (int kt = 0; kt < ND; kt += 64) {
#pragma unroll
    for (int i = 0; i < 4; ++i) {
      __builtin_amdgcn_global_load_lds(
          (const __attribute__((address_space(1))) void*)(gA + (size_t)(i * 32) * ND + kt),
          (__attribute__((address_space(3))) void*)(As + (i * 32 + wave * 8) * 64), 16, 0, 0);
      __builtin_amdgcn_global_load_lds(
          (const __attribute__((address_space(1))) void*)(gB + (size_t)(i * 32) * ND + kt),
          (__attribute__((address_space(3))) void*)(Bs + (i * 32 + wave * 8) * 64), 16, 0, 0);
    }
    __syncthreads();
#pragma unroll
    for (int kk = 0; kk < 64; kk += 32) {
      const int kof = kk + ((lane >> 4) << 3);
      const int rA = (wm << 6) + (lane & 15);
      const int rB = (wn << 6) + (lane & 15);
      bf16x8 a[4], bvv[4];
#pragma unroll
      for (int m = 0; m < 4; ++m)
        a[m] = *(const bf16x8*)&As[(rA + (m << 4)) * 64 + kof];
#pragma unroll
      for (int n = 0; n < 4; ++n)
        bvv[n] = *(const bf16x8*)&Bs[(rB + (n << 4)) * 64 + kof];
#pragma unroll
      for (int m = 0; m < 4; ++m)
#pragma unroll
        for (int n = 0; n < 4; ++n)
          acc[m][n] = __builtin_amdgcn_mfma_f32_16x16x32_bf16(a[m], bvv[n], acc[m][n], 0, 0, 0);
    }
    __syncthreads();
  }

  const int c0 = bcol + (wn << 6) + (lane & 15);
  const int r0 = brow + (wm << 6) + ((lane >> 4) << 2);
#pragma unroll
  for (int n = 0; n < 4; ++n) {
    float bet = beta[c0 + (n << 4)];
#pragma unroll
    for (int m = 0; m < 4; ++m) {
#pragma unroll
      for (int r = 0; r < 4; ++r) {
        float v = fmaxf(acc[m][n][r] + bet, 0.f);
        acts[(size_t)(r0 + (m << 4) + r) * NF + c0 + (n << 4)] = f2bf(v);
      }
    }
  }
}

// ---------------------------------------------------------------------------
// K1: one wave per row. Exact k-th bf16 key via 15-probe bitwise binary
// search (register-resident), then emit candidate indices (margin 0.25).
// Candidate SET is deterministic; append order doesn't matter (K2's
// selection is order-independent).
__global__ __launch_bounds__(256) void k1_cand(
    const unsigned short* __restrict__ acts, const int* __restrict__ kptr,
    unsigned short* __restrict__ cand, int* __restrict__ counts) {
  const int tid = threadIdx.x, wave = tid >> 6, lane = tid & 63;
  const int b = blockIdx.x * 4 + wave;
  int k = *kptr; k = k < 1 ? 1 : (k > 64 ? 64 : k);
  __shared__ int cnt[4];
  if (lane == 0) cnt[wave] = 0;

  uint4 kv[16];
  const uint4* row = (const uint4*)(acts + (size_t)b * NF);
#pragma unroll
  for (int i = 0; i < 16; ++i) kv[i] = row[lane + 64 * i];

  unsigned T = 0;
  for (int bit = 14; bit >= 0; --bit) {
    unsigned probe = T | (1u << bit);
    int c = 0;
#pragma unroll
    for (int i = 0; i < 16; ++i) {
      const unsigned* w = (const unsigned*)&kv[i];
#pragma unroll
      for (int q = 0; q < 4; ++q) {
        c += ((w[q] & 0xFFFFu) >= probe);
        c += ((w[q] >> 16) >= probe);
      }
    }
#pragma unroll
    for (int off = 32; off; off >>= 1) c += __shfl_down(c, off);
    c = __shfl(c, 0);
    if (c >= k) T = probe;
  }
  const float thr = __uint_as_float(T << 16) - 0.25f;

  unsigned short* crow = cand + (size_t)b * MAXC;
#pragma unroll
  for (int i = 0; i < 16; ++i) {
    const unsigned* w = (const unsigned*)&kv[i];
#pragma unroll
    for (int q = 0; q < 4; ++q) {
#pragma unroll
      for (int h = 0; h < 2; ++h) {
        unsigned u = h ? (w[q] >> 16) : (w[q] & 0xFFFFu);
        if (u && __uint_as_float(u << 16) >= thr) {
          int s = atomicAdd(&cnt[wave], 1);
          if (s < MAXC) crow[s] = (unsigned short)((lane + 64 * i) * 8 + q * 2 + h);
        }
      }
    }
  }
  if (lane == 0) counts[b] = cnt[wave] < MAXC ? cnt[wave] : MAXC;
}

// ---------------------------------------------------------------------------
// K2: exact fp32 recompute of candidates, top-k select (val desc, idx asc),
// fused reconstruction. W_enc + WdecT (50 MB) stay L3-resident: the only
// stream here is x (48 MB).
__global__ __launch_bounds__(256) void k2_exact(
    const unsigned short* __restrict__ cand, const int* __restrict__ counts,
    const float* __restrict__ x, const float* __restrict__ W_enc,
    const float* __restrict__ beta, const float* __restrict__ WdecT,
    const float* __restrict__ dec_bias, const int* __restrict__ kptr,
    float* __restrict__ out_rec, float* __restrict__ g_vals, int* __restrict__ g_idxs) {
  const int b = blockIdx.x, tid = threadIdx.x;
  const int lane = tid & 63, wave = tid >> 6;
  int k = *kptr; k = k < 1 ? 1 : (k > 64 ? 64 : k);

  __shared__ unsigned short cidx[MAXC];
  __shared__ float cval[MAXC];
  __shared__ float selv[64];
  __shared__ int seli[64];
  __shared__ unsigned long long wred64[4];

  int n = counts[b];
  if (n > MAXC) n = MAXC;
  for (int i = tid; i < n; i += 256) cidx[i] = cand[(size_t)b * MAXC + i];
  __syncthreads();

  float xr[12];
#pragma unroll
  for (int c = 0; c < 12; ++c) xr[c] = x[(size_t)b * ND + lane + 64 * c];
  for (int j = wave; j < n; j += 4) {
    const int f = cidx[j];
    const float* wr = W_enc + (size_t)f * ND;
    float s = 0.f;
#pragma unroll
    for (int c = 0; c < 12; ++c) s = fmaf(xr[c], wr[lane + 64 * c], s);
    for (int off = 32; off; off >>= 1) s += __shfl_down(s, off);
    if (lane == 0) cval[j] = s + beta[f];
  }
  __syncthreads();

  for (int r = 0; r < k; ++r) {
    unsigned long long best = 0ull;
    for (int j = tid; j < n; j += 256) {
      float cv = cval[j];
      unsigned long long p;
      if (cv < -1e29f) p = 0ull;
      else {
        float pv = fmaxf(cv, 0.f);
        p = (((unsigned long long)__float_as_uint(pv)) << 13) | (unsigned)(8191 - cidx[j]);
      }
      if (p > best) best = p;
    }
    for (int off = 32; off; off >>= 1) {
      unsigned long long o = __shfl_down(best, off);
      if (o > best) best = o;
    }
    if (lane == 0) wred64[wave] = best;
    __syncthreads();
    unsigned long long m = wred64[0];
#pragma unroll
    for (int w = 1; w < 4; ++w)
      if (wred64[w] > m) m = wred64[w];
    if (tid == 0) {
      if (m) { selv[r] = __uint_as_float((unsigned)(m >> 13)); seli[r] = 8191 - (int)(m & 0x1FFFull); }
      else   { selv[r] = 0.f; seli[r] = 0; }
    }
    if (m) {
      int wf = 8191 - (int)(m & 0x1FFFull);
      for (int j = tid; j < n; j += 256)
        if (cidx[j] == (unsigned short)wf) cval[j] = -1e30f;
    }
    __syncthreads();
  }

#pragma unroll
  for (int c = 0; c < 3; ++c) {
    int d = tid + 256 * c;
    float a = dec_bias[d];
    for (int r = 0; r < k; ++r) a = fmaf(selv[r], WdecT[(size_t)seli[r] * ND + d], a);
    out_rec[(size_t)b * ND + d] = a;
  }
  if (tid < k) {
    g_vals[b * 64 + tid] = selv[tid];
    g_idxs[b * 64 + tid] = seli[tid];
  }
}

// ---------------------------------------------------------------------------
__global__ __launch_bounds__(256) void d2_sparse_k(
    const float* __restrict__ g_vals, const int* __restrict__ g_idxs,
    const int* __restrict__ kptr, float* __restrict__ out_sc) {
  const int b = blockIdx.x, tid = threadIdx.x;
  int k = *kptr; k = k < 1 ? 1 : (k > 64 ? 64 : k);
  __shared__ float row[NF];
  __shared__ float sv[64];
  __shared__ int si[64];
  if (tid < k) { sv[tid] = g_vals[b * 64 + tid]; si[tid] = g_idxs[b * 64 + tid]; }
  float4* r4 = (float4*)row;
#pragma unroll
  for (int i = 0; i < 8; ++i) r4[tid + 256 * i] = make_float4(0.f, 0.f, 0.f, 0.f);
  __syncthreads();
  if (tid < k) row[si[tid]] = sv[tid];
  __syncthreads();
  float4* o4 = (float4*)(out_sc + (size_t)b * NF);
#pragma unroll
  for (int i = 0; i < 8; ++i) o4[tid + 256 * i] = r4[tid + 256 * i];
}

// ---------------------------------------------------------------------------
extern "C" void kernel_launch(void* const* d_in, const int* in_sizes, int n_in,
                              void* d_out, int out_size, void* d_ws, size_t ws_size,
                              hipStream_t stream) {
  const float* x        = (const float*)d_in[0];
  const float* W_enc    = (const float*)d_in[1];
  const float* b_enc    = (const float*)d_in[2];
  const float* W_dec    = (const float*)d_in[3];
  const float* dec_bias = (const float*)d_in[4];
  const int*   kptr     = (const int*)d_in[5];

  float* out_rec = (float*)d_out;
  float* out_sc  = (float*)d_out + (size_t)NB * ND;

  // scratch carved from the sparse-code output region (overwritten by d2 last)
  char* scb = (char*)out_sc;
  unsigned short* acts  = (unsigned short*)scb;                // 256 MB
  unsigned short* Xbf   = (unsigned short*)(scb + 268435456);  // 24 MB
  unsigned short* Wbf   = (unsigned short*)(scb + 293601280);  // 12 MB
  unsigned short* cand  = (unsigned short*)(scb + 306184192);  // 32 MB
  int*            cnts  = (int*)(scb + 339738624);             // 64 KB

  char* ws = (char*)d_ws;
  float* WdecT  = (float*)ws;                 // 25,165,824 B
  float* beta   = (float*)(ws + 25165824);    //     32,768 B
  float* g_vals = (float*)(ws + 25198592);    //  4,194,304 B
  int*   g_idxs = (int*)(ws + 29392896);      //  4,194,304 B

  cvt_bf16_k<<<(NB * ND) / 2048, 256, 0, stream>>>(x, Xbf);
  cvt_bf16_k<<<(NF * ND) / 2048, 256, 0, stream>>>(W_enc, Wbf);
  beta_k<<<NF / 4, 256, 0, stream>>>(W_enc, b_enc, dec_bias, beta);
  transpose_k<<<dim3(NF / 32, ND / 32), 256, 0, stream>>>(W_dec, WdecT, ND, NF);
  enc_gemm_bf16<<<dim3(NF / 128, NB / 128), 256, 0, stream>>>(Xbf, Wbf, beta, acts);
  k1_cand<<<NB / 4, 256, 0, stream>>>(acts, kptr, cand, cnts);
  k2_exact<<<NB, 256, 0, stream>>>(cand, cnts, x, W_enc, beta, WdecT, dec_bias, kptr,
                                   out_rec, g_vals, g_idxs);
  d2_sparse_k<<<NB, 256, 0, stream>>>(g_vals, g_idxs, kptr, out_sc);
}

// Round 4
// 882.354 us; speedup vs baseline: 1.4338x; 1.4338x over previous
//
#include <hip/hip_runtime.h>

#define NB 16384
#define ND 768
#define NF 8192
#define AMAX 256   // ambiguous candidates cap per row
#define WMAX 64    // winners cap per row
#define MARG 0.07f // classification margin (>= 2x bf16-GEMM error bound)

typedef __attribute__((ext_vector_type(8))) short bf16x8;
typedef __attribute__((ext_vector_type(4))) float f32x4;

__device__ inline unsigned short f2bf(float f) {
  unsigned u = __float_as_uint(f);
  unsigned r = (u + 0x7FFFu + ((u >> 16) & 1u)) >> 16;
  return (unsigned short)r;
}
__device__ inline float bfbits2f(unsigned u16) { return __uint_as_float(u16 << 16); }

// ---------------------------------------------------------------------------
__global__ __launch_bounds__(256) void cvt_bf16_k(const float* __restrict__ in,
                                                  unsigned short* __restrict__ out) {
  size_t t = (size_t)blockIdx.x * 256 + threadIdx.x;
  const float4* i4 = (const float4*)in;
  float4 a = i4[t * 2], b = i4[t * 2 + 1];
  ushort4 lo = make_ushort4(f2bf(a.x), f2bf(a.y), f2bf(a.z), f2bf(a.w));
  ushort4 hi = make_ushort4(f2bf(b.x), f2bf(b.y), f2bf(b.z), f2bf(b.w));
  ((ushort4*)out)[t * 2] = lo;
  ((ushort4*)out)[t * 2 + 1] = hi;
}

// ---------------------------------------------------------------------------
__global__ __launch_bounds__(256) void beta_k(const float* __restrict__ W_enc,
                                              const float* __restrict__ b_enc,
                                              const float* __restrict__ dec_bias,
                                              float* __restrict__ beta) {
  int f = blockIdx.x * 4 + (threadIdx.x >> 6);
  int lane = threadIdx.x & 63;
  const float* wr = W_enc + (size_t)f * ND;
  float s = 0.f;
  for (int d = lane; d < ND; d += 64) s += dec_bias[d] * wr[d];
  for (int off = 32; off; off >>= 1) s += __shfl_down(s, off);
  if (lane == 0) beta[f] = b_enc[f] - s;
}

// ---------------------------------------------------------------------------
// transpose W_dec [ND][NF] fp32 -> WdecBf [NF][ND] bf16
__global__ __launch_bounds__(256) void transpose_bf_k(const float* __restrict__ in,
                                                      unsigned short* __restrict__ out) {
  __shared__ float tile[32][33];
  int lx = threadIdx.x & 31;
  int ty = threadIdx.x >> 5;
  int x = blockIdx.x * 32 + lx;  // f
  for (int j = ty; j < 32; j += 8) {
    int y = blockIdx.y * 32 + j;  // d
    tile[j][lx] = in[(size_t)y * NF + x];
  }
  __syncthreads();
  int xo = blockIdx.y * 32 + lx;  // d
  for (int j = ty; j < 32; j += 8) {
    int yo = blockIdx.x * 32 + j;  // f
    out[(size_t)yo * ND + xo] = f2bf(tile[lx][j]);
  }
}

// ---------------------------------------------------------------------------
// bf16 MFMA GEMM (m97 structure) + XCD-aware bijective swizzle.
__global__ __launch_bounds__(256) void enc_gemm_bf16(
    const unsigned short* __restrict__ Xb, const unsigned short* __restrict__ Wb,
    const float* __restrict__ beta, unsigned short* __restrict__ acts) {
  __shared__ __align__(1024) unsigned short As[128 * 64];
  __shared__ __align__(1024) unsigned short Bs[128 * 64];
  const int tid = threadIdx.x;
  const int wave = tid >> 6, lane = tid & 63;
  const int wm = wave >> 1, wn = wave & 1;

  const int nwg = gridDim.x * gridDim.y;
  const int orig = blockIdx.y * gridDim.x + blockIdx.x;
  const int tileid = (orig & 7) * (nwg >> 3) + (orig >> 3);
  const int brow = (tileid / gridDim.x) << 7;
  const int bcol = (tileid % gridDim.x) << 7;

  f32x4 acc[4][4] = {};

  const int srow = tid >> 3;
  const int scol = (tid & 7) << 3;
  const unsigned short* gA = Xb + (size_t)(brow + srow) * ND + scol;
  const unsigned short* gB = Wb + (size_t)(bcol + srow) * ND + scol;

  for (int kt = 0; kt < ND; kt += 64) {
#pragma unroll
    for (int i = 0; i < 4; ++i) {
      __builtin_amdgcn_global_load_lds(
          (const __attribute__((address_space(1))) void*)(gA + (size_t)(i * 32) * ND + kt),
          (__attribute__((address_space(3))) void*)(As + (i * 32 + wave * 8) * 64), 16, 0, 0);
      __builtin_amdgcn_global_load_lds(
          (const __attribute__((address_space(1))) void*)(gB + (size_t)(i * 32) * ND + kt),
          (__attribute__((address_space(3))) void*)(Bs + (i * 32 + wave * 8) * 64), 16, 0, 0);
    }
    __syncthreads();
#pragma unroll
    for (int kk = 0; kk < 64; kk += 32) {
      const int kof = kk + ((lane >> 4) << 3);
      const int rA = (wm << 6) + (lane & 15);
      const int rB = (wn << 6) + (lane & 15);
      bf16x8 a[4], bvv[4];
#pragma unroll
      for (int m = 0; m < 4; ++m)
        a[m] = *(const bf16x8*)&As[(rA + (m << 4)) * 64 + kof];
#pragma unroll
      for (int n = 0; n < 4; ++n)
        bvv[n] = *(const bf16x8*)&Bs[(rB + (n << 4)) * 64 + kof];
#pragma unroll
      for (int m = 0; m < 4; ++m)
#pragma unroll
        for (int n = 0; n < 4; ++n)
          acc[m][n] = __builtin_amdgcn_mfma_f32_16x16x32_bf16(a[m], bvv[n], acc[m][n], 0, 0, 0);
    }
    __syncthreads();
  }

  const int c0 = bcol + (wn << 6) + (lane & 15);
  const int r0 = brow + (wm << 6) + ((lane >> 4) << 2);
#pragma unroll
  for (int n = 0; n < 4; ++n) {
    float bet = beta[c0 + (n << 4)];
#pragma unroll
    for (int m = 0; m < 4; ++m) {
#pragma unroll
      for (int r = 0; r < 4; ++r) {
        float v = fmaxf(acc[m][n][r] + bet, 0.f);
        acts[(size_t)(r0 + (m << 4) + r) * NF + c0 + (n << 4)] = f2bf(v);
      }
    }
  }
}

// ---------------------------------------------------------------------------
// ksel: wave-per-row fused {exact bf16 k-th via 2-level histogram, W/A
// classification with margin, exact fp32 dots for ambiguous only, in-wave
// selection, bf16-gather reconstruction}.
__global__ __launch_bounds__(256, 5) void ksel_k(
    const unsigned short* __restrict__ acts, const float* __restrict__ x,
    const float* __restrict__ W_enc, const float* __restrict__ beta,
    const unsigned short* __restrict__ WdecBf, const float* __restrict__ dec_bias,
    const int* __restrict__ kptr,
    float* __restrict__ out_rec, float* __restrict__ g_vals, int* __restrict__ g_idxs) {
  const int tid = threadIdx.x, wave = tid >> 6, lane = tid & 63;
  const int b = blockIdx.x * 4 + wave;
  int k = *kptr; k = k < 1 ? 1 : (k > 64 ? 64 : k);
  const unsigned kk = (unsigned)k;

  __shared__ unsigned hist_s[4][256];
  __shared__ unsigned long long alist_s[4][AMAX];
  __shared__ unsigned wlist_s[4][WMAX];
  __shared__ float selv_s[4][64];
  __shared__ int seli_s[4][64];

  unsigned* hist = hist_s[wave];
  unsigned long long* alist = alist_s[wave];
  unsigned* wlist = wlist_s[wave];
  float* selv = selv_s[wave];
  int* seli = seli_s[wave];

  // load the row's 8192 bf16 keys: 16 uint4 per lane
  uint4 kv[16];
  {
    const uint4* row4 = (const uint4*)(acts + (size_t)b * NF);
#pragma unroll
    for (int i = 0; i < 16; ++i) kv[i] = row4[lane + 64 * i];
  }

  // ---- pass A: 256-bin exponent histogram (key>>7), skip exact zeros
#pragma unroll
  for (int i = 0; i < 4; ++i) hist[lane + 64 * i] = 0;
  __syncthreads();
#pragma unroll
  for (int i = 0; i < 16; ++i) {
    const unsigned* w = (const unsigned*)&kv[i];
#pragma unroll
    for (int q = 0; q < 4; ++q) {
      unsigned lo = w[q] & 0xFFFFu, hi = w[q] >> 16;
      if (lo) atomicAdd(&hist[lo >> 7], 1u);
      if (hi) atomicAdd(&hist[hi >> 7], 1u);
    }
  }
  __syncthreads();
  // suffix-scan: lane owns bins [4l..4l+3]
  unsigned h0 = hist[lane * 4], h1 = hist[lane * 4 + 1];
  unsigned h2 = hist[lane * 4 + 2], h3 = hist[lane * 4 + 3];
  unsigned s = h0 + h1 + h2 + h3;
  unsigned S = s;
#pragma unroll
  for (int off = 1; off < 64; off <<= 1) {
    unsigned t = __shfl_down(S, off);
    if (lane + off < 64) S += t;
  }
  int myebin = -1; unsigned myab = 0;
  {
    unsigned run = S - s;  // keys strictly above own top bin
    unsigned hh[4] = {h3, h2, h1, h0};
#pragma unroll
    for (int j = 0; j < 4; ++j) {
      unsigned nrun = run + hh[j];
      if (run < kk && nrun >= kk) { myebin = lane * 4 + (3 - j); myab = run; }
      run = nrun;
    }
  }
  unsigned long long mvA = __ballot(myebin >= 0);
  int srcA = mvA ? (__ffsll((unsigned long long)mvA) - 1) : 0;
  int ebinW = __shfl(myebin, srcA);
  unsigned aboveW = __shfl(myab, srcA);
  int validA = (mvA != 0ull);
  __syncthreads();

  // ---- pass B: 128-bin mantissa histogram restricted to exp bin e*
#pragma unroll
  for (int i = 0; i < 4; ++i) hist[lane + 64 * i] = 0;
  __syncthreads();
#pragma unroll
  for (int i = 0; i < 16; ++i) {
    const unsigned* w = (const unsigned*)&kv[i];
#pragma unroll
    for (int q = 0; q < 4; ++q) {
      unsigned lo = w[q] & 0xFFFFu, hi = w[q] >> 16;
      if (lo && (int)(lo >> 7) == ebinW) atomicAdd(&hist[lo & 127], 1u);
      if (hi && (int)(hi >> 7) == ebinW) atomicAdd(&hist[hi & 127], 1u);
    }
  }
  __syncthreads();
  unsigned g0 = hist[lane * 2], g1 = hist[lane * 2 + 1];
  unsigned s2 = g0 + g1;
  unsigned S2 = s2;
#pragma unroll
  for (int off = 1; off < 64; off <<= 1) {
    unsigned t = __shfl_down(S2, off);
    if (lane + off < 64) S2 += t;
  }
  int mymbin = -1;
  {
    unsigned run = (S2 - s2) + aboveW;
    unsigned gg[2] = {g1, g0};
#pragma unroll
    for (int j = 0; j < 2; ++j) {
      unsigned nrun = run + gg[j];
      if (run < kk && nrun >= kk) mymbin = lane * 2 + (1 - j);
      run = nrun;
    }
  }
  unsigned long long mvB = __ballot(mymbin >= 0);
  int srcB = mvB ? (__ffsll((unsigned long long)mvB) - 1) : 0;
  int mbin = __shfl(mymbin, srcB);
  unsigned taukey = (validA && mvB) ? (((unsigned)ebinW << 7) | (unsigned)mbin) : 0u;
  const float tauf = bfbits2f(taukey);
  const float thrW = tauf + MARG;
  const float thrA = tauf - MARG;
  __syncthreads();

  // ---- pass C: classify + deterministic lane-major append
  unsigned cntW = 0, cntA = 0;
#pragma unroll
  for (int i = 0; i < 16; ++i) {
    const unsigned* w = (const unsigned*)&kv[i];
#pragma unroll
    for (int q = 0; q < 4; ++q) {
#pragma unroll
      for (int h = 0; h < 2; ++h) {
        unsigned u = h ? (w[q] >> 16) : (w[q] & 0xFFFFu);
        float v = bfbits2f(u);
        if (v > thrW) ++cntW;
        else if (v >= thrA) ++cntA;
      }
    }
  }
  unsigned iW = cntW, iA = cntA;
#pragma unroll
  for (int off = 1; off < 64; off <<= 1) {
    unsigned tw = __shfl_up(iW, off), ta = __shfl_up(iA, off);
    if (lane >= off) { iW += tw; iA += ta; }
  }
  unsigned baseW = iW - cntW, baseA = iA - cntA;
  unsigned cW = __shfl(iW, 63);
  unsigned naT = __shfl(iA, 63);
  unsigned c = cW < WMAX ? cW : WMAX;   // proof: cW <= k-1; cap for safety
  if (c > kk) c = kk;
  unsigned na = naT < AMAX ? naT : AMAX;
  {
    unsigned pw = baseW, pa = baseA;
#pragma unroll
    for (int i = 0; i < 16; ++i) {
      const unsigned* w = (const unsigned*)&kv[i];
#pragma unroll
      for (int q = 0; q < 4; ++q) {
#pragma unroll
        for (int h = 0; h < 2; ++h) {
          unsigned u = h ? (w[q] >> 16) : (w[q] & 0xFFFFu);
          float v = bfbits2f(u);
          unsigned idx = (unsigned)(lane + 64 * i) * 8 + q * 2 + h;
          if (v > thrW) { if (pw < WMAX) wlist[pw] = (u << 16) | idx; ++pw; }
          else if (v >= thrA) { if (pa < AMAX) alist[pa] = (unsigned long long)idx; ++pa; }
        }
      }
    }
  }
  __syncthreads();

  // ---- exact fp32 dots for ambiguous (2-wide pipelined)
  float xr[12];
#pragma unroll
  for (int cc = 0; cc < 12; ++cc) xr[cc] = x[(size_t)b * ND + lane + 64 * cc];
  for (unsigned j = 0; j < na; j += 2) {
    int f0 = (int)(unsigned)alist[j];
    int f1 = (j + 1 < na) ? (int)(unsigned)alist[j + 1] : f0;
    const float* w0 = W_enc + (size_t)f0 * ND;
    const float* w1 = W_enc + (size_t)f1 * ND;
    float s0 = 0.f, s1 = 0.f;
#pragma unroll
    for (int cc = 0; cc < 12; ++cc) {
      s0 = fmaf(xr[cc], w0[lane + 64 * cc], s0);
      s1 = fmaf(xr[cc], w1[lane + 64 * cc], s1);
    }
#pragma unroll
    for (int off = 32; off; off >>= 1) {
      s0 += __shfl_xor(s0, off);
      s1 += __shfl_xor(s1, off);
    }
    if (lane == 0) {
      float v0 = fmaxf(s0 + beta[f0], 0.f);
      alist[j] = (((unsigned long long)__float_as_uint(v0)) << 13) | (unsigned)(8191 - f0);
      if (j + 1 < na) {
        float v1 = fmaxf(s1 + beta[f1], 0.f);
        alist[j + 1] = (((unsigned long long)__float_as_uint(v1)) << 13) | (unsigned)(8191 - f1);
      }
    }
  }
  __syncthreads();

  // ---- winners -> sel list (bf16 values suffice: |err| << 0.12 threshold)
  for (unsigned t = lane; t < c; t += 64) {
    unsigned wv = wlist[t];
    selv[t] = __uint_as_float(wv & 0xFFFF0000u);
    seli[t] = (int)(wv & 0xFFFFu);
  }
  __syncthreads();

  // ---- select top (k-c) ambiguous by (exact val desc, idx asc), in-wave
  {
    unsigned long long p0 = 0, p1 = 0, p2 = 0, p3 = 0;
    if (lane < (int)na) p0 = alist[lane];
    if (lane + 64 < (int)na) p1 = alist[lane + 64];
    if (lane + 128 < (int)na) p2 = alist[lane + 128];
    if (lane + 192 < (int)na) p3 = alist[lane + 192];
    int rounds = k - (int)c; if (rounds < 0) rounds = 0;
    for (int r = 0; r < rounds; ++r) {
      unsigned long long m = p0;
      if (p1 > m) m = p1;
      if (p2 > m) m = p2;
      if (p3 > m) m = p3;
#pragma unroll
      for (int off = 32; off; off >>= 1) {
        unsigned long long o = __shfl_xor(m, off);
        if (o > m) m = o;
      }
      if (lane == 0) {
        selv[c + r] = __uint_as_float((unsigned)(m >> 13));
        seli[c + r] = 8191 - (int)(m & 0x1FFFull);
      }
      if (p0 == m) p0 = 0;
      if (p1 == m) p1 = 0;
      if (p2 == m) p2 = 0;
      if (p3 == m) p3 = 0;
    }
  }
  __syncthreads();

  if (lane < k) {
    g_vals[(size_t)b * 64 + lane] = selv[lane];
    g_idxs[(size_t)b * 64 + lane] = seli[lane];
  }

  // ---- reconstruction: rec[d] = dec_bias[d] + sum_r selv[r]*WdecBf[seli[r]][d]
  float acc[12];
#pragma unroll
  for (int cc = 0; cc < 6; ++cc) {
    float2 db = *(const float2*)&dec_bias[cc * 128 + lane * 2];
    acc[2 * cc] = db.x; acc[2 * cc + 1] = db.y;
  }
#define RECON_TERM(r)                                                          \
  {                                                                            \
    int f = seli[r]; float v = selv[r];                                        \
    const unsigned short* wd = WdecBf + (size_t)f * ND;                        \
    _Pragma("unroll")                                                          \
    for (int cc = 0; cc < 6; ++cc) {                                           \
      unsigned pr = *(const unsigned*)&wd[cc * 128 + lane * 2];                \
      acc[2 * cc] = fmaf(v, bfbits2f(pr & 0xFFFFu), acc[2 * cc]);              \
      acc[2 * cc + 1] = fmaf(v, bfbits2f(pr >> 16), acc[2 * cc + 1]);          \
    }                                                                          \
  }
  if (k == 32) {
#pragma unroll
    for (int r = 0; r < 32; ++r) RECON_TERM(r)
  } else {
    for (int r = 0; r < k; ++r) RECON_TERM(r)
  }
#pragma unroll
  for (int cc = 0; cc < 6; ++cc) {
    float2 st = make_float2(acc[2 * cc], acc[2 * cc + 1]);
    *(float2*)&out_rec[(size_t)b * ND + cc * 128 + lane * 2] = st;
  }
}

// ---------------------------------------------------------------------------
__global__ __launch_bounds__(256) void d2_sparse_k(
    const float* __restrict__ g_vals, const int* __restrict__ g_idxs,
    const int* __restrict__ kptr, float* __restrict__ out_sc) {
  const int b = blockIdx.x, tid = threadIdx.x;
  int k = *kptr; k = k < 1 ? 1 : (k > 64 ? 64 : k);
  __shared__ float row[NF];
  __shared__ float sv[64];
  __shared__ int si[64];
  if (tid < k) { sv[tid] = g_vals[(size_t)b * 64 + tid]; si[tid] = g_idxs[(size_t)b * 64 + tid]; }
  float4* r4 = (float4*)row;
#pragma unroll
  for (int i = 0; i < 8; ++i) r4[tid + 256 * i] = make_float4(0.f, 0.f, 0.f, 0.f);
  __syncthreads();
  if (tid < k) row[si[tid]] = sv[tid];
  __syncthreads();
  float4* o4 = (float4*)(out_sc + (size_t)b * NF);
#pragma unroll
  for (int i = 0; i < 8; ++i) o4[tid + 256 * i] = r4[tid + 256 * i];
}

// ---------------------------------------------------------------------------
extern "C" void kernel_launch(void* const* d_in, const int* in_sizes, int n_in,
                              void* d_out, int out_size, void* d_ws, size_t ws_size,
                              hipStream_t stream) {
  const float* x        = (const float*)d_in[0];
  const float* W_enc    = (const float*)d_in[1];
  const float* b_enc    = (const float*)d_in[2];
  const float* W_dec    = (const float*)d_in[3];
  const float* dec_bias = (const float*)d_in[4];
  const int*   kptr     = (const int*)d_in[5];

  float* out_rec = (float*)d_out;
  float* out_sc  = (float*)d_out + (size_t)NB * ND;

  // scratch carved from the sparse-code output region (rewritten by d2 last)
  char* scb = (char*)out_sc;
  unsigned short* acts = (unsigned short*)scb;                // 256 MB
  unsigned short* Xbf  = (unsigned short*)(scb + 268435456);  // 24 MB
  unsigned short* Wbf  = (unsigned short*)(scb + 293601280);  // 12 MB

  char* ws = (char*)d_ws;
  unsigned short* WdecBf = (unsigned short*)ws;        // 12,582,912 B
  float* beta   = (float*)(ws + 12582912);             //     32,768 B
  float* g_vals = (float*)(ws + 12615680);             //  4,194,304 B
  int*   g_idxs = (int*)(ws + 16809984);               //  4,194,304 B

  cvt_bf16_k<<<(NB * ND) / 2048, 256, 0, stream>>>(x, Xbf);
  cvt_bf16_k<<<(NF * ND) / 2048, 256, 0, stream>>>(W_enc, Wbf);
  beta_k<<<NF / 4, 256, 0, stream>>>(W_enc, b_enc, dec_bias, beta);
  transpose_bf_k<<<dim3(NF / 32, ND / 32), 256, 0, stream>>>(W_dec, WdecBf);
  enc_gemm_bf16<<<dim3(NF / 128, NB / 128), 256, 0, stream>>>(Xbf, Wbf, beta, acts);
  ksel_k<<<NB / 4, 256, 0, stream>>>(acts, x, W_enc, beta, WdecBf, dec_bias, kptr,
                                     out_rec, g_vals, g_idxs);
  d2_sparse_k<<<NB, 256, 0, stream>>>(g_vals, g_idxs, kptr, out_sc);
}

// Round 6
// 809.062 us; speedup vs baseline: 1.5637x; 1.0906x over previous
//
#include <hip/hip_runtime.h>

#define NB 16384
#define ND 768
#define NF 8192
#define CMAX 512   // compact candidate list cap per row (expect ~220)
#define AMAX 128   // ambiguous cap per row (expect ~13)
#define MARG 0.07f // classification margin (>= 2x bf16-GEMM act error bound)

typedef __attribute__((ext_vector_type(8))) short bf16x8;
typedef __attribute__((ext_vector_type(4))) float f32x4;
typedef __attribute__((ext_vector_type(4))) unsigned int u32x4;
typedef __attribute__((ext_vector_type(2))) float f32x2;

__device__ inline unsigned short f2bf(float f) {
  unsigned u = __float_as_uint(f);
  unsigned r = (u + 0x7FFFu + ((u >> 16) & 1u)) >> 16;
  return (unsigned short)r;
}
__device__ inline float bfbits2f(unsigned u16) { return __uint_as_float(u16 << 16); }

// ---------------------------------------------------------------------------
__global__ __launch_bounds__(256) void cvt_bf16_k(const float* __restrict__ in,
                                                  unsigned short* __restrict__ out) {
  size_t t = (size_t)blockIdx.x * 256 + threadIdx.x;
  const float4* i4 = (const float4*)in;
  float4 a = i4[t * 2], b = i4[t * 2 + 1];
  ushort4 lo = make_ushort4(f2bf(a.x), f2bf(a.y), f2bf(a.z), f2bf(a.w));
  ushort4 hi = make_ushort4(f2bf(b.x), f2bf(b.y), f2bf(b.z), f2bf(b.w));
  ((ushort4*)out)[t * 2] = lo;
  ((ushort4*)out)[t * 2 + 1] = hi;
}

// ---------------------------------------------------------------------------
__global__ __launch_bounds__(256) void beta_k(const float* __restrict__ W_enc,
                                              const float* __restrict__ b_enc,
                                              const float* __restrict__ dec_bias,
                                              float* __restrict__ beta) {
  int f = blockIdx.x * 4 + (threadIdx.x >> 6);
  int lane = threadIdx.x & 63;
  const float* wr = W_enc + (size_t)f * ND;
  float s = 0.f;
  for (int d = lane; d < ND; d += 64) s += dec_bias[d] * wr[d];
  for (int off = 32; off; off >>= 1) s += __shfl_down(s, off);
  if (lane == 0) beta[f] = b_enc[f] - s;
}

// ---------------------------------------------------------------------------
// transpose W_dec [ND][NF] fp32 -> WdecBf [NF][ND] bf16
__global__ __launch_bounds__(256) void transpose_bf_k(const float* __restrict__ in,
                                                      unsigned short* __restrict__ out) {
  __shared__ float tile[32][33];
  int lx = threadIdx.x & 31;
  int ty = threadIdx.x >> 5;
  int x = blockIdx.x * 32 + lx;  // f
  for (int j = ty; j < 32; j += 8) {
    int y = blockIdx.y * 32 + j;  // d
    tile[j][lx] = in[(size_t)y * NF + x];
  }
  __syncthreads();
  int xo = blockIdx.y * 32 + lx;  // d
  for (int j = ty; j < 32; j += 8) {
    int yo = blockIdx.x * 32 + j;  // f
    out[(size_t)yo * ND + xo] = f2bf(tile[lx][j]);
  }
}

// ---------------------------------------------------------------------------
// bf16 MFMA GEMM (m97 structure) + XCD-aware bijective swizzle; nt stores so
// the 256 MB acts stream doesn't pollute L2/L3 (keep weights resident).
__global__ __launch_bounds__(256) void enc_gemm_bf16(
    const unsigned short* __restrict__ Xb, const unsigned short* __restrict__ Wb,
    const float* __restrict__ beta, unsigned short* __restrict__ acts) {
  __shared__ __align__(1024) unsigned short As[128 * 64];
  __shared__ __align__(1024) unsigned short Bs[128 * 64];
  const int tid = threadIdx.x;
  const int wave = tid >> 6, lane = tid & 63;
  const int wm = wave >> 1, wn = wave & 1;

  const int nwg = gridDim.x * gridDim.y;
  const int orig = blockIdx.y * gridDim.x + blockIdx.x;
  const int tileid = (orig & 7) * (nwg >> 3) + (orig >> 3);
  const int brow = (tileid / gridDim.x) << 7;
  const int bcol = (tileid % gridDim.x) << 7;

  f32x4 acc[4][4] = {};

  const int srow = tid >> 3;
  const int scol = (tid & 7) << 3;
  const unsigned short* gA = Xb + (size_t)(brow + srow) * ND + scol;
  const unsigned short* gB = Wb + (size_t)(bcol + srow) * ND + scol;

  for (int kt = 0; kt < ND; kt += 64) {
#pragma unroll
    for (int i = 0; i < 4; ++i) {
      __builtin_amdgcn_global_load_lds(
          (const __attribute__((address_space(1))) void*)(gA + (size_t)(i * 32) * ND + kt),
          (__attribute__((address_space(3))) void*)(As + (i * 32 + wave * 8) * 64), 16, 0, 0);
      __builtin_amdgcn_global_load_lds(
          (const __attribute__((address_space(1))) void*)(gB + (size_t)(i * 32) * ND + kt),
          (__attribute__((address_space(3))) void*)(Bs + (i * 32 + wave * 8) * 64), 16, 0, 0);
    }
    __syncthreads();
#pragma unroll
    for (int kk = 0; kk < 64; kk += 32) {
      const int kof = kk + ((lane >> 4) << 3);
      const int rA = (wm << 6) + (lane & 15);
      const int rB = (wn << 6) + (lane & 15);
      bf16x8 a[4], bvv[4];
#pragma unroll
      for (int m = 0; m < 4; ++m)
        a[m] = *(const bf16x8*)&As[(rA + (m << 4)) * 64 + kof];
#pragma unroll
      for (int n = 0; n < 4; ++n)
        bvv[n] = *(const bf16x8*)&Bs[(rB + (n << 4)) * 64 + kof];
#pragma unroll
      for (int m = 0; m < 4; ++m)
#pragma unroll
        for (int n = 0; n < 4; ++n)
          acc[m][n] = __builtin_amdgcn_mfma_f32_16x16x32_bf16(a[m], bvv[n], acc[m][n], 0, 0, 0);
    }
    __syncthreads();
  }

  const int c0 = bcol + (wn << 6) + (lane & 15);
  const int r0 = brow + (wm << 6) + ((lane >> 4) << 2);
#pragma unroll
  for (int n = 0; n < 4; ++n) {
    float bet = beta[c0 + (n << 4)];
#pragma unroll
    for (int m = 0; m < 4; ++m) {
#pragma unroll
      for (int r = 0; r < 4; ++r) {
        float v = fmaxf(acc[m][n][r] + bet, 0.f);
        __builtin_nontemporal_store(
            f2bf(v), &acts[(size_t)(r0 + (m << 4) + r) * NF + c0 + (n << 4)]);
      }
    }
  }
}

// ---------------------------------------------------------------------------
// ksel v2: wave-per-row, STREAMING (nothing held across passes in regs).
// pass1: 256-binade LDS hist -> e* (binade of bf16 k-th).
// pass2: compact all v >= 2^e* - MARG into LDS list (~220 entries; superset
//        of winners+ambiguous since tau >= 2^e*).
// then: exact bf16 tau from list, classify, exact fp32 dots for ambiguous,
//       in-wave selection, fused bf16-gather reconstruction.
__global__ __launch_bounds__(256, 6) void ksel_k(
    const unsigned short* __restrict__ acts, const float* __restrict__ x,
    const float* __restrict__ W_enc, const float* __restrict__ beta,
    const unsigned short* __restrict__ WdecBf, const float* __restrict__ dec_bias,
    const int* __restrict__ kptr,
    float* __restrict__ out_rec, float* __restrict__ g_vals, int* __restrict__ g_idxs) {
  const int tid = threadIdx.x, wave = tid >> 6, lane = tid & 63;
  const int b = blockIdx.x * 4 + wave;
  int k = *kptr; k = k < 1 ? 1 : (k > 64 ? 64 : k);
  const unsigned kk = (unsigned)k;

  __shared__ unsigned hist_s[4][256];
  __shared__ unsigned clist_s[4][CMAX];
  __shared__ unsigned long long aval_s[4][AMAX];
  __shared__ float selv_s[4][64];
  __shared__ int seli_s[4][64];
  __shared__ int ctrC_s[4], ctrW_s[4], ctrA_s[4];

  unsigned* hist = hist_s[wave];
  unsigned* clist = clist_s[wave];
  unsigned long long* aval = aval_s[wave];
  float* selv = selv_s[wave];
  int* seli = seli_s[wave];

  const u32x4* row4 = (const u32x4*)(acts + (size_t)b * NF);

  // ---- pass 1: binade histogram (skip zeros), nt stream
#pragma unroll
  for (int i = 0; i < 4; ++i) hist[lane + 64 * i] = 0;
  if (lane == 0) { ctrC_s[wave] = 0; ctrW_s[wave] = 0; ctrA_s[wave] = 0; }
  __syncthreads();
#pragma unroll 4
  for (int i = 0; i < 16; ++i) {
    u32x4 v = __builtin_nontemporal_load(&row4[lane + 64 * i]);
#pragma unroll
    for (int q = 0; q < 4; ++q) {
      unsigned lo = v[q] & 0xFFFFu, hi = v[q] >> 16;
      if (lo) atomicAdd(&hist[lo >> 7], 1u);
      if (hi) atomicAdd(&hist[hi >> 7], 1u);
    }
  }
  __syncthreads();

  // suffix-scan 256 bins (lane owns 4) -> e* = binade containing k-th largest
  unsigned h0 = hist[lane * 4], h1 = hist[lane * 4 + 1];
  unsigned h2 = hist[lane * 4 + 2], h3 = hist[lane * 4 + 3];
  unsigned s = h0 + h1 + h2 + h3;
  unsigned S = s;
#pragma unroll
  for (int off = 1; off < 64; off <<= 1) {
    unsigned t = __shfl_down(S, off);
    if (lane + off < 64) S += t;
  }
  int myebin = -1;
  {
    unsigned run = S - s;
    unsigned hh[4] = {h3, h2, h1, h0};
#pragma unroll
    for (int j = 0; j < 4; ++j) {
      unsigned nrun = run + hh[j];
      if (run < kk && nrun >= kk) myebin = lane * 4 + (3 - j);
      run = nrun;
    }
  }
  unsigned long long mvA = __ballot(myebin >= 0);
  int srcA = mvA ? (__ffsll(mvA) - 1) : 0;
  int ebinW = __shfl(myebin, srcA);
  if (mvA == 0ull) ebinW = 0;  // degenerate (unreachable on real data)
  float floor_thr = (mvA != 0ull) ? (bfbits2f((unsigned)ebinW << 7) - MARG) : -1.f;

  // ---- pass 2: compact candidates (v >= floor_thr), nt stream (L2-hot)
#pragma unroll 4
  for (int i = 0; i < 16; ++i) {
    u32x4 v = __builtin_nontemporal_load(&row4[lane + 64 * i]);
#pragma unroll
    for (int q = 0; q < 4; ++q) {
#pragma unroll
      for (int h = 0; h < 2; ++h) {
        unsigned u = h ? (v[q] >> 16) : (v[q] & 0xFFFFu);
        if (bfbits2f(u) >= floor_thr) {
          int p = atomicAdd(&ctrC_s[wave], 1);
          if (p < CMAX) clist[p] = (u << 16) | (unsigned)((lane + 64 * i) * 8 + q * 2 + h);
        }
      }
    }
  }
  __syncthreads();
  int n = ctrC_s[wave]; if (n > CMAX) n = CMAX;

  // ---- exact bf16 tau from compact list: mantissa hist within binade e*
  hist[lane * 2] = 0; hist[lane * 2 + 1] = 0;
  __syncthreads();
  unsigned cab = 0;  // count strictly above binade e*
  for (int j = lane; j < n; j += 64) {
    unsigned key = clist[j] >> 16;
    int bin = (int)(key >> 7);
    if (bin > ebinW) ++cab;
    else if (bin == ebinW) atomicAdd(&hist[key & 127], 1u);
  }
#pragma unroll
  for (int off = 32; off; off >>= 1) cab += __shfl_xor(cab, off);
  __syncthreads();
  unsigned g0 = hist[lane * 2], g1 = hist[lane * 2 + 1];
  unsigned s2 = g0 + g1;
  unsigned S2 = s2;
#pragma unroll
  for (int off = 1; off < 64; off <<= 1) {
    unsigned t = __shfl_down(S2, off);
    if (lane + off < 64) S2 += t;
  }
  int mymbin = -1;
  {
    unsigned run = (S2 - s2) + cab;
    unsigned gg[2] = {g1, g0};
#pragma unroll
    for (int j = 0; j < 2; ++j) {
      unsigned nrun = run + gg[j];
      if (run < kk && nrun >= kk) mymbin = lane * 2 + (1 - j);
      run = nrun;
    }
  }
  unsigned long long mvB = __ballot(mymbin >= 0);
  int srcB = mvB ? (__ffsll(mvB) - 1) : 0;
  int mbin = __shfl(mymbin, srcB);
  if (mvB == 0ull) mbin = 0;
  const float tauf = bfbits2f(((unsigned)ebinW << 7) | (unsigned)mbin);
  const float thrW = tauf + MARG;
  const float thrA = tauf - MARG;

  // ---- classify compact list: winners (bf16 val final) / ambiguous
  for (int j = lane; j < n; j += 64) {
    unsigned e = clist[j];
    float v = bfbits2f(e >> 16);
    int idx = (int)(e & 0xFFFFu);
    if (v > thrW) {
      int p = atomicAdd(&ctrW_s[wave], 1);
      if (p < 63) { selv[p] = v; seli[p] = idx; }  // proof: c <= k-1
    } else if (v >= thrA) {
      int p = atomicAdd(&ctrA_s[wave], 1);
      if (p < AMAX) aval[p] = (unsigned long long)(unsigned)idx;
    }
  }
  __syncthreads();
  int c = ctrW_s[wave]; if (c > 63) c = 63; if (c > k - 1) c = k - 1;
  int na = ctrA_s[wave]; if (na > AMAX) na = AMAX;

  // ---- exact fp32 dots for ambiguous (2-wide)
  float xr[12];
#pragma unroll
  for (int cc = 0; cc < 12; ++cc)
    xr[cc] = __builtin_nontemporal_load(&x[(size_t)b * ND + lane + 64 * cc]);
  for (int j = 0; j < na; j += 2) {
    int f0 = (int)(unsigned)aval[j];
    int f1 = (j + 1 < na) ? (int)(unsigned)aval[j + 1] : f0;
    const float* w0 = W_enc + (size_t)f0 * ND;
    const float* w1 = W_enc + (size_t)f1 * ND;
    float s0 = 0.f, s1 = 0.f;
#pragma unroll
    for (int cc = 0; cc < 12; ++cc) {
      s0 = fmaf(xr[cc], w0[lane + 64 * cc], s0);
      s1 = fmaf(xr[cc], w1[lane + 64 * cc], s1);
    }
#pragma unroll
    for (int off = 32; off; off >>= 1) {
      s0 += __shfl_xor(s0, off);
      s1 += __shfl_xor(s1, off);
    }
    if (lane == 0) {
      float v0 = fmaxf(s0 + beta[f0], 0.f);
      aval[j] = (((unsigned long long)__float_as_uint(v0)) << 13) | (unsigned)(8191 - f0);
      if (j + 1 < na) {
        float v1 = fmaxf(s1 + beta[f1], 0.f);
        aval[j + 1] = (((unsigned long long)__float_as_uint(v1)) << 13) | (unsigned)(8191 - f1);
      }
    }
  }
  __syncthreads();

  // ---- select top (k-c) ambiguous by (exact val desc, idx asc)
  {
    unsigned long long p0 = (lane < na) ? aval[lane] : 0ull;
    unsigned long long p1 = (lane + 64 < na) ? aval[lane + 64] : 0ull;
    int rounds = k - c; if (rounds < 0) rounds = 0;
    for (int r = 0; r < rounds; ++r) {
      unsigned long long m = p0 > p1 ? p0 : p1;
#pragma unroll
      for (int off = 32; off; off >>= 1) {
        unsigned long long o = __shfl_xor(m, off);
        if (o > m) m = o;
      }
      if (lane == 0) {
        if (m) { selv[c + r] = __uint_as_float((unsigned)(m >> 13)); seli[c + r] = 8191 - (int)(m & 0x1FFFull); }
        else   { selv[c + r] = 0.f; seli[c + r] = 0; }
      }
      if (p0 == m) p0 = 0;
      if (p1 == m) p1 = 0;
    }
  }
  __syncthreads();

  if (lane < k) {
    g_vals[(size_t)b * 64 + lane] = selv[lane];
    g_idxs[(size_t)b * 64 + lane] = seli[lane];
  }

  // ---- fused reconstruction (bf16 decoder gathers, cached)
  float acc[12];
#pragma unroll
  for (int cc = 0; cc < 6; ++cc) {
    float2 db = *(const float2*)&dec_bias[cc * 128 + lane * 2];
    acc[2 * cc] = db.x; acc[2 * cc + 1] = db.y;
  }
#define RECON_TERM(r)                                                          \
  {                                                                            \
    int f = seli[r]; float v = selv[r];                                        \
    const unsigned short* wd = WdecBf + (size_t)f * ND;                        \
    _Pragma("unroll")                                                          \
    for (int cc = 0; cc < 6; ++cc) {                                           \
      unsigned pr = *(const unsigned*)&wd[cc * 128 + lane * 2];                \
      acc[2 * cc] = fmaf(v, bfbits2f(pr & 0xFFFFu), acc[2 * cc]);              \
      acc[2 * cc + 1] = fmaf(v, bfbits2f(pr >> 16), acc[2 * cc + 1]);          \
    }                                                                          \
  }
  if (k == 32) {
#pragma unroll
    for (int r = 0; r < 32; ++r) RECON_TERM(r)
  } else {
    for (int r = 0; r < k; ++r) RECON_TERM(r)
  }
#pragma unroll
  for (int cc = 0; cc < 6; ++cc) {
    f32x2 st = {acc[2 * cc], acc[2 * cc + 1]};
    __builtin_nontemporal_store(st, (f32x2*)&out_rec[(size_t)b * ND + cc * 128 + lane * 2]);
  }
}

// ---------------------------------------------------------------------------
__global__ __launch_bounds__(256) void d2_sparse_k(
    const float* __restrict__ g_vals, const int* __restrict__ g_idxs,
    const int* __restrict__ kptr, float* __restrict__ out_sc) {
  const int b = blockIdx.x, tid = threadIdx.x;
  int k = *kptr; k = k < 1 ? 1 : (k > 64 ? 64 : k);
  __shared__ float row[NF];
  __shared__ float sv[64];
  __shared__ int si[64];
  if (tid < k) { sv[tid] = g_vals[(size_t)b * 64 + tid]; si[tid] = g_idxs[(size_t)b * 64 + tid]; }
  float4* r4 = (float4*)row;
#pragma unroll
  for (int i = 0; i < 8; ++i) r4[tid + 256 * i] = make_float4(0.f, 0.f, 0.f, 0.f);
  __syncthreads();
  if (tid < k) row[si[tid]] = sv[tid];
  __syncthreads();
  f32x4* o4 = (f32x4*)(out_sc + (size_t)b * NF);
  const f32x4* r4v = (const f32x4*)row;
#pragma unroll
  for (int i = 0; i < 8; ++i)
    __builtin_nontemporal_store(r4v[tid + 256 * i], &o4[tid + 256 * i]);
}

// ---------------------------------------------------------------------------
extern "C" void kernel_launch(void* const* d_in, const int* in_sizes, int n_in,
                              void* d_out, int out_size, void* d_ws, size_t ws_size,
                              hipStream_t stream) {
  const float* x        = (const float*)d_in[0];
  const float* W_enc    = (const float*)d_in[1];
  const float* b_enc    = (const float*)d_in[2];
  const float* W_dec    = (const float*)d_in[3];
  const float* dec_bias = (const float*)d_in[4];
  const int*   kptr     = (const int*)d_in[5];

  float* out_rec = (float*)d_out;
  float* out_sc  = (float*)d_out + (size_t)NB * ND;

  // scratch carved from the sparse-code output region (rewritten by d2 last)
  char* scb = (char*)out_sc;
  unsigned short* acts = (unsigned short*)scb;                // 256 MB
  unsigned short* Xbf  = (unsigned short*)(scb + 268435456);  // 24 MB
  unsigned short* Wbf  = (unsigned short*)(scb + 293601280);  // 12 MB

  char* ws = (char*)d_ws;
  unsigned short* WdecBf = (unsigned short*)ws;        // 12,582,912 B
  float* beta   = (float*)(ws + 12582912);             //     32,768 B
  float* g_vals = (float*)(ws + 12615680);             //  4,194,304 B
  int*   g_idxs = (int*)(ws + 16809984);               //  4,194,304 B

  cvt_bf16_k<<<(NB * ND) / 2048, 256, 0, stream>>>(x, Xbf);
  cvt_bf16_k<<<(NF * ND) / 2048, 256, 0, stream>>>(W_enc, Wbf);
  beta_k<<<NF / 4, 256, 0, stream>>>(W_enc, b_enc, dec_bias, beta);
  transpose_bf_k<<<dim3(NF / 32, ND / 32), 256, 0, stream>>>(W_dec, WdecBf);
  enc_gemm_bf16<<<dim3(NF / 128, NB / 128), 256, 0, stream>>>(Xbf, Wbf, beta, acts);
  ksel_k<<<NB / 4, 256, 0, stream>>>(acts, x, W_enc, beta, WdecBf, dec_bias, kptr,
                                     out_rec, g_vals, g_idxs);
  d2_sparse_k<<<NB, 256, 0, stream>>>(g_vals, g_idxs, kptr, out_sc);
}

// Round 8
// 601.871 us; speedup vs baseline: 2.1020x; 1.3442x over previous
//
#include <hip/hip_runtime.h>

#define NB 16384
#define ND 768
#define NF 8192
#define CMAX 512   // compact candidate list cap per row
#define AMAX 128   // ambiguous cap per row (expect ~13)
#define MARG 0.07f // classification margin (>= 2x bf16-GEMM act error bound)

typedef __attribute__((ext_vector_type(8))) short bf16x8;
typedef __attribute__((ext_vector_type(4))) float f32x4;
typedef __attribute__((ext_vector_type(4))) unsigned int u32x4;
typedef __attribute__((ext_vector_type(2))) float f32x2;

__device__ inline unsigned short f2bf(float f) {
  unsigned u = __float_as_uint(f);
  unsigned r = (u + 0x7FFFu + ((u >> 16) & 1u)) >> 16;
  return (unsigned short)r;
}
__device__ inline float bfbits2f(unsigned u16) { return __uint_as_float(u16 << 16); }

// ---------------------------------------------------------------------------
__global__ __launch_bounds__(256) void cvt_bf16_k(const float* __restrict__ in,
                                                  unsigned short* __restrict__ out) {
  size_t t = (size_t)blockIdx.x * 256 + threadIdx.x;
  const float4* i4 = (const float4*)in;
  float4 a = i4[t * 2], b = i4[t * 2 + 1];
  ushort4 lo = make_ushort4(f2bf(a.x), f2bf(a.y), f2bf(a.z), f2bf(a.w));
  ushort4 hi = make_ushort4(f2bf(b.x), f2bf(b.y), f2bf(b.z), f2bf(b.w));
  ((ushort4*)out)[t * 2] = lo;
  ((ushort4*)out)[t * 2 + 1] = hi;
}

// ---------------------------------------------------------------------------
__global__ __launch_bounds__(256) void beta_k(const float* __restrict__ W_enc,
                                              const float* __restrict__ b_enc,
                                              const float* __restrict__ dec_bias,
                                              float* __restrict__ beta) {
  int f = blockIdx.x * 4 + (threadIdx.x >> 6);
  int lane = threadIdx.x & 63;
  const float* wr = W_enc + (size_t)f * ND;
  float s = 0.f;
  for (int d = lane; d < ND; d += 64) s += dec_bias[d] * wr[d];
  for (int off = 32; off; off >>= 1) s += __shfl_down(s, off);
  if (lane == 0) beta[f] = b_enc[f] - s;
}

// ---------------------------------------------------------------------------
__global__ __launch_bounds__(256) void transpose_bf_k(const float* __restrict__ in,
                                                      unsigned short* __restrict__ out) {
  __shared__ float tile[32][33];
  int lx = threadIdx.x & 31;
  int ty = threadIdx.x >> 5;
  int x = blockIdx.x * 32 + lx;  // f
  for (int j = ty; j < 32; j += 8) {
    int y = blockIdx.y * 32 + j;  // d
    tile[j][lx] = in[(size_t)y * NF + x];
  }
  __syncthreads();
  int xo = blockIdx.y * 32 + lx;  // d
  for (int j = ty; j < 32; j += 8) {
    int yo = blockIdx.x * 32 + j;  // f
    out[(size_t)yo * ND + xo] = f2bf(tile[lx][j]);
  }
}

// ---------------------------------------------------------------------------
// bf16 MFMA GEMM v3 (fixed epilogue readout):
//  - XCD chunk column-major tile order (B panel reused 16x, A set L2-resident)
//  - LDS XOR swizzle (pre-swizzled global source + swizzled frag read)
//  - LDS-staged vectorized epilogue + fused per-(row,tile) max -> tmax
__global__ __launch_bounds__(256) void enc_gemm_bf16(
    const unsigned short* __restrict__ Xb, const unsigned short* __restrict__ Wb,
    const float* __restrict__ beta, unsigned short* __restrict__ acts,
    unsigned short* __restrict__ tmax) {
  __shared__ __align__(1024) unsigned short SL[2][128 * 64];
  unsigned short* As = SL[0];
  unsigned short* Bs = SL[1];
  const int tid = threadIdx.x;
  const int wave = tid >> 6, lane = tid & 63;
  const int wm = wave >> 1, wn = wave & 1;

  const int orig = blockIdx.y * gridDim.x + blockIdx.x;  // 0..8191
  const int xcd = orig & 7;
  const int local = orig >> 3;          // 0..1023
  const int tcol = local >> 4;          // 0..63
  const int trow = (xcd << 4) + (local & 15);
  const int brow = trow << 7;
  const int bcol = tcol << 7;

  f32x4 acc[4][4] = {};

  const int srow = tid >> 3;                                   // 0..31
  const int scol = (((tid & 7) ^ ((tid >> 3) & 7)) << 3);      // pre-swizzled source chunk
  const unsigned short* gA = Xb + (size_t)(brow + srow) * ND + scol;
  const unsigned short* gB = Wb + (size_t)(bcol + srow) * ND + scol;

  for (int kt = 0; kt < ND; kt += 64) {
#pragma unroll
    for (int i = 0; i < 4; ++i) {
      __builtin_amdgcn_global_load_lds(
          (const __attribute__((address_space(1))) void*)(gA + (size_t)(i * 32) * ND + kt),
          (__attribute__((address_space(3))) void*)(As + (i * 32 + wave * 8) * 64), 16, 0, 0);
      __builtin_amdgcn_global_load_lds(
          (const __attribute__((address_space(1))) void*)(gB + (size_t)(i * 32) * ND + kt),
          (__attribute__((address_space(3))) void*)(Bs + (i * 32 + wave * 8) * 64), 16, 0, 0);
    }
    __syncthreads();
#pragma unroll
    for (int kk = 0; kk < 64; kk += 32) {
      const int chunk = (kk + ((lane >> 4) << 3)) >> 3;  // 0..7 (16B units)
      const int rA = (wm << 6) + (lane & 15);
      const int rB = (wn << 6) + (lane & 15);
      const int sw = chunk ^ (lane & 7);  // row&7 == lane&7 for all frag rows
      bf16x8 a[4], bvv[4];
#pragma unroll
      for (int m = 0; m < 4; ++m)
        a[m] = *(const bf16x8*)&As[(rA + (m << 4)) * 64 + (sw << 3)];
#pragma unroll
      for (int n = 0; n < 4; ++n)
        bvv[n] = *(const bf16x8*)&Bs[(rB + (n << 4)) * 64 + (sw << 3)];
#pragma unroll
      for (int m = 0; m < 4; ++m)
#pragma unroll
        for (int n = 0; n < 4; ++n)
          acc[m][n] = __builtin_amdgcn_mfma_f32_16x16x32_bf16(a[m], bvv[n], acc[m][n], 0, 0, 0);
    }
    __syncthreads();
  }

  // ---- epilogue: acc -> LDS (swizzled 16B slots), then coalesced stores + tmax
  unsigned short* S = (unsigned short*)SL;  // 128 x 128 shorts (32 KB)
#pragma unroll
  for (int n = 0; n < 4; ++n) {
    float bet = beta[bcol + (wn << 6) + (n << 4) + (lane & 15)];
#pragma unroll
    for (int m = 0; m < 4; ++m) {
#pragma unroll
      for (int r = 0; r < 4; ++r) {
        int row_l = (wm << 6) + (m << 4) + ((lane >> 4) << 2) + r;
        int col_l = (wn << 6) + (n << 4) + (lane & 15);
        float v = fmaxf(acc[m][n][r] + bet, 0.f);
        int slot = (col_l >> 3) ^ (row_l & 7);  // XOR affects low 3 bits only
        S[row_l * 128 + (slot << 3) + (col_l & 7)] = f2bf(v);
      }
    }
  }
  __syncthreads();
  // full coverage: 8 iters x (16 rows x 16 slots) = 128 rows x 16 chunks
#pragma unroll
  for (int i = 0; i < 8; ++i) {
    int row_l = (tid >> 4) + (i << 4);
    int slot = tid & 15;
    u32x4 d = *(const u32x4*)&S[row_l * 128 + (slot << 3)];
    unsigned mx = 0;
#pragma unroll
    for (int q = 0; q < 4; ++q) {
      unsigned lo = d[q] & 0xFFFFu, hi = d[q] >> 16;
      if (lo > mx) mx = lo;
      if (hi > mx) mx = hi;
    }
#pragma unroll
    for (int off = 1; off < 16; off <<= 1) {
      unsigned o = __shfl_xor(mx, off);
      if (o > mx) mx = o;
    }
    int chunk = slot ^ (row_l & 7);  // logical 16B chunk this slot holds
    __builtin_nontemporal_store(
        d, (u32x4*)&acts[(size_t)(brow + row_l) * NF + bcol + (chunk << 3)]);
    if (slot == 0) tmax[(size_t)(brow + row_l) * 64 + tcol] = (unsigned short)mx;
  }
}

// ---------------------------------------------------------------------------
// tkth: per row, L = k-th largest of the 64 tile maxima (provably <= tau).
__global__ __launch_bounds__(256) void tkth_k(const unsigned short* __restrict__ tmax,
                                              const int* __restrict__ kptr,
                                              float* __restrict__ Lthr) {
  const int wave = threadIdx.x >> 6, lane = threadIdx.x & 63;
  const int b = blockIdx.x * 4 + wave;
  int k = *kptr; k = k < 1 ? 1 : (k > 64 ? 64 : k);
  unsigned key = tmax[(size_t)b * 64 + lane];
  unsigned T = 0;
  for (int bit = 14; bit >= 0; --bit) {
    unsigned probe = T | (1u << bit);
    int c = __popcll(__ballot(key >= probe));
    if (c >= k) T = probe;
  }
  if (lane == 0) Lthr[b] = bfbits2f(T) - MARG;
}

// ---------------------------------------------------------------------------
// ksel v3: wave-per-row, single streaming pass with tile skipping.
__global__ __launch_bounds__(256, 6) void ksel_k(
    const unsigned short* __restrict__ acts, const unsigned short* __restrict__ tmax,
    const float* __restrict__ Lthr, const float* __restrict__ x,
    const float* __restrict__ W_enc, const float* __restrict__ beta,
    const unsigned short* __restrict__ WdecBf, const float* __restrict__ dec_bias,
    const int* __restrict__ kptr,
    float* __restrict__ out_rec, float* __restrict__ g_vals, int* __restrict__ g_idxs) {
  const int tid = threadIdx.x, wave = tid >> 6, lane = tid & 63;
  const int b = blockIdx.x * 4 + wave;
  int k = *kptr; k = k < 1 ? 1 : (k > 64 ? 64 : k);
  const unsigned kk = (unsigned)k;

  __shared__ int stile_s[4][64];
  __shared__ unsigned clist_s[4][CMAX];
  __shared__ unsigned long long aval_s[4][AMAX];
  __shared__ float selv_s[4][64];
  __shared__ int seli_s[4][64];
  __shared__ int ctrC_s[4], ctrW_s[4], ctrA_s[4];

  int* stile = stile_s[wave];
  unsigned* clist = clist_s[wave];
  unsigned long long* aval = aval_s[wave];
  float* selv = selv_s[wave];
  int* seli = seli_s[wave];

  if (lane == 0) { ctrC_s[wave] = 0; ctrW_s[wave] = 0; ctrA_s[wave] = 0; }
  const float Lf = Lthr[b];

  // ---- tile selection from tmax
  {
    unsigned short tm = tmax[(size_t)b * 64 + lane];
    bool sel = bfbits2f(tm) >= Lf;
    unsigned long long mask = __ballot(sel);
    int pos = __popcll(mask & ((1ull << lane) - 1ull));
    if (sel) stile[pos] = lane;
  }
  __syncthreads();
  const int nsel = __popcll(__ballot(bfbits2f(tmax[(size_t)b * 64 + lane]) >= Lf));

  // ---- single streaming pass over selected tiles (4 tiles / iteration)
  const u32x4* row16 = (const u32x4*)(acts + (size_t)b * NF);  // 16 x u32x4 per tile
  for (int t = 0; t < nsel; t += 4) {
    int tt = t + (lane >> 4);
    if (tt < nsel) {
      int tile = stile[tt];
      u32x4 v = __builtin_nontemporal_load(&row16[tile * 16 + (lane & 15)]);
      int base = tile * 128 + (lane & 15) * 8;
#pragma unroll
      for (int q = 0; q < 4; ++q) {
#pragma unroll
        for (int h = 0; h < 2; ++h) {
          unsigned u = h ? (v[q] >> 16) : (v[q] & 0xFFFFu);
          if (bfbits2f(u) >= Lf) {
            int p = atomicAdd(&ctrC_s[wave], 1);
            if (p < CMAX) clist[p] = (u << 16) | (unsigned)(base + q * 2 + h);
          }
        }
      }
    }
  }
  __syncthreads();
  int n = ctrC_s[wave]; if (n > CMAX) n = CMAX;

  // ---- exact bf16 tau: 15-probe binary search over the compact list
  unsigned ks[8];
#pragma unroll
  for (int ii = 0; ii < 8; ++ii) {
    int j = lane + (ii << 6);
    ks[ii] = (j < n) ? (clist[j] >> 16) : 0u;
  }
  unsigned T = 0;
  for (int bit = 14; bit >= 0; --bit) {
    unsigned probe = T | (1u << bit);
    int c = 0;
#pragma unroll
    for (int ii = 0; ii < 8; ++ii) c += (ks[ii] >= probe);
#pragma unroll
    for (int off = 32; off; off >>= 1) c += __shfl_xor(c, off);
    if (c >= (int)kk) T = probe;
  }
  const float tauf = bfbits2f(T);
  const float thrW = tauf + MARG;
  const float thrA = tauf - MARG;

  // ---- classify: winners (bf16 value final) / ambiguous band
  for (int j = lane; j < n; j += 64) {
    unsigned e = clist[j];
    float v = bfbits2f(e >> 16);
    int idx = (int)(e & 0xFFFFu);
    if (v > thrW) {
      int p = atomicAdd(&ctrW_s[wave], 1);
      if (p < 63) { selv[p] = v; seli[p] = idx; }  // count(v > tau) <= k-1
    } else if (v >= thrA) {
      int p = atomicAdd(&ctrA_s[wave], 1);
      if (p < AMAX) aval[p] = (unsigned long long)(unsigned)idx;
    }
  }
  __syncthreads();
  int c = ctrW_s[wave]; if (c > 63) c = 63; if (c > k - 1) c = k - 1;
  int na = ctrA_s[wave]; if (na > AMAX) na = AMAX;

  // ---- exact fp32 dots for ambiguous (2-wide)
  float xr[12];
#pragma unroll
  for (int cc = 0; cc < 12; ++cc)
    xr[cc] = __builtin_nontemporal_load(&x[(size_t)b * ND + lane + 64 * cc]);
  for (int j = 0; j < na; j += 2) {
    int f0 = (int)(unsigned)aval[j];
    int f1 = (j + 1 < na) ? (int)(unsigned)aval[j + 1] : f0;
    const float* w0 = W_enc + (size_t)f0 * ND;
    const float* w1 = W_enc + (size_t)f1 * ND;
    float s0 = 0.f, s1 = 0.f;
#pragma unroll
    for (int cc = 0; cc < 12; ++cc) {
      s0 = fmaf(xr[cc], w0[lane + 64 * cc], s0);
      s1 = fmaf(xr[cc], w1[lane + 64 * cc], s1);
    }
#pragma unroll
    for (int off = 32; off; off >>= 1) {
      s0 += __shfl_xor(s0, off);
      s1 += __shfl_xor(s1, off);
    }
    if (lane == 0) {
      float v0 = fmaxf(s0 + beta[f0], 0.f);
      aval[j] = (((unsigned long long)__float_as_uint(v0)) << 13) | (unsigned)(8191 - f0);
      if (j + 1 < na) {
        float v1 = fmaxf(s1 + beta[f1], 0.f);
        aval[j + 1] = (((unsigned long long)__float_as_uint(v1)) << 13) | (unsigned)(8191 - f1);
      }
    }
  }
  __syncthreads();

  // ---- select top (k-c) ambiguous by (exact val desc, idx asc)
  {
    unsigned long long p0 = (lane < na) ? aval[lane] : 0ull;
    unsigned long long p1 = (lane + 64 < na) ? aval[lane + 64] : 0ull;
    int rounds = k - c; if (rounds < 0) rounds = 0;
    for (int r = 0; r < rounds; ++r) {
      unsigned long long m = p0 > p1 ? p0 : p1;
#pragma unroll
      for (int off = 32; off; off >>= 1) {
        unsigned long long o = __shfl_xor(m, off);
        if (o > m) m = o;
      }
      if (lane == 0) {
        if (m) { selv[c + r] = __uint_as_float((unsigned)(m >> 13)); seli[c + r] = 8191 - (int)(m & 0x1FFFull); }
        else   { selv[c + r] = 0.f; seli[c + r] = 0; }
      }
      if (p0 == m) p0 = 0;
      if (p1 == m) p1 = 0;
    }
  }
  __syncthreads();

  if (lane < k) {
    g_vals[(size_t)b * 64 + lane] = selv[lane];
    g_idxs[(size_t)b * 64 + lane] = seli[lane];
  }

  // ---- fused reconstruction (bf16 decoder gathers, cached)
  float acc[12];
#pragma unroll
  for (int cc = 0; cc < 6; ++cc) {
    float2 db = *(const float2*)&dec_bias[cc * 128 + lane * 2];
    acc[2 * cc] = db.x; acc[2 * cc + 1] = db.y;
  }
#define RECON_TERM(r)                                                          \
  {                                                                            \
    int f = seli[r]; float v = selv[r];                                        \
    const unsigned short* wd = WdecBf + (size_t)f * ND;                        \
    _Pragma("unroll")                                                          \
    for (int cc = 0; cc < 6; ++cc) {                                           \
      unsigned pr = *(const unsigned*)&wd[cc * 128 + lane * 2];                \
      acc[2 * cc] = fmaf(v, bfbits2f(pr & 0xFFFFu), acc[2 * cc]);              \
      acc[2 * cc + 1] = fmaf(v, bfbits2f(pr >> 16), acc[2 * cc + 1]);          \
    }                                                                          \
  }
  if (k == 32) {
#pragma unroll
    for (int r = 0; r < 32; ++r) RECON_TERM(r)
  } else {
    for (int r = 0; r < k; ++r) RECON_TERM(r)
  }
#pragma unroll
  for (int cc = 0; cc < 6; ++cc) {
    f32x2 st = {acc[2 * cc], acc[2 * cc + 1]};
    __builtin_nontemporal_store(st, (f32x2*)&out_rec[(size_t)b * ND + cc * 128 + lane * 2]);
  }
}

// ---------------------------------------------------------------------------
__global__ __launch_bounds__(256) void d2_sparse_k(
    const float* __restrict__ g_vals, const int* __restrict__ g_idxs,
    const int* __restrict__ kptr, float* __restrict__ out_sc) {
  const int b = blockIdx.x, tid = threadIdx.x;
  int k = *kptr; k = k < 1 ? 1 : (k > 64 ? 64 : k);
  __shared__ float row[NF];
  __shared__ float sv[64];
  __shared__ int si[64];
  if (tid < k) { sv[tid] = g_vals[(size_t)b * 64 + tid]; si[tid] = g_idxs[(size_t)b * 64 + tid]; }
  float4* r4 = (float4*)row;
#pragma unroll
  for (int i = 0; i < 8; ++i) r4[tid + 256 * i] = make_float4(0.f, 0.f, 0.f, 0.f);
  __syncthreads();
  if (tid < k) row[si[tid]] = sv[tid];
  __syncthreads();
  f32x4* o4 = (f32x4*)(out_sc + (size_t)b * NF);
  const f32x4* r4v = (const f32x4*)row;
#pragma unroll
  for (int i = 0; i < 8; ++i)
    __builtin_nontemporal_store(r4v[tid + 256 * i], &o4[tid + 256 * i]);
}

// ---------------------------------------------------------------------------
extern "C" void kernel_launch(void* const* d_in, const int* in_sizes, int n_in,
                              void* d_out, int out_size, void* d_ws, size_t ws_size,
                              hipStream_t stream) {
  const float* x        = (const float*)d_in[0];
  const float* W_enc    = (const float*)d_in[1];
  const float* b_enc    = (const float*)d_in[2];
  const float* W_dec    = (const float*)d_in[3];
  const float* dec_bias = (const float*)d_in[4];
  const int*   kptr     = (const int*)d_in[5];

  float* out_rec = (float*)d_out;
  float* out_sc  = (float*)d_out + (size_t)NB * ND;

  // scratch carved from the sparse-code output region (rewritten by d2 last)
  char* scb = (char*)out_sc;
  unsigned short* acts = (unsigned short*)scb;                // 256 MB
  unsigned short* Xbf  = (unsigned short*)(scb + 268435456);  // 24 MB
  unsigned short* Wbf  = (unsigned short*)(scb + 293601280);  // 12 MB

  char* ws = (char*)d_ws;
  unsigned short* WdecBf = (unsigned short*)ws;        // 12,582,912 B
  float* beta   = (float*)(ws + 12582912);             //     32,768 B
  float* g_vals = (float*)(ws + 12615680);             //  4,194,304 B
  int*   g_idxs = (int*)(ws + 16809984);               //  4,194,304 B
  unsigned short* tmax = (unsigned short*)(ws + 21004288); // 2,097,152 B
  float* Lthr  = (float*)(ws + 23101440);              //     65,536 B

  cvt_bf16_k<<<(NB * ND) / 2048, 256, 0, stream>>>(x, Xbf);
  cvt_bf16_k<<<(NF * ND) / 2048, 256, 0, stream>>>(W_enc, Wbf);
  beta_k<<<NF / 4, 256, 0, stream>>>(W_enc, b_enc, dec_bias, beta);
  transpose_bf_k<<<dim3(NF / 32, ND / 32), 256, 0, stream>>>(W_dec, WdecBf);
  enc_gemm_bf16<<<dim3(NF / 128, NB / 128), 256, 0, stream>>>(Xbf, Wbf, beta, acts, tmax);
  tkth_k<<<NB / 4, 256, 0, stream>>>(tmax, kptr, Lthr);
  ksel_k<<<NB / 4, 256, 0, stream>>>(acts, tmax, Lthr, x, W_enc, beta, WdecBf, dec_bias,
                                     kptr, out_rec, g_vals, g_idxs);
  d2_sparse_k<<<NB, 256, 0, stream>>>(g_vals, g_idxs, kptr, out_sc);
}